// Round 3
// baseline (252.677 us; speedup 1.0000x reference)
//
#include <hip/hip_runtime.h>
#include <math.h>

#define BB 8
#define NN 2048
#define WWID 64
#define RNUM 4
#define CTRL 272      // R*W + R + R*3
#define EPSF 1e-8f
#define TI 32         // rows per K3 block
#define TILES 64      // NN/TI
#define CQ 4          // column quarters in K3 (512 cols each)

__device__ __forceinline__ float wred_sum(float v){
#pragma unroll
  for (int m=1;m<64;m<<=1) v += __shfl_xor(v,m);
  return v;
}
__device__ __forceinline__ float wred_max(float v){
#pragma unroll
  for (int m=1;m<64;m<<=1) v = fmaxf(v, __shfl_xor(v,m));
  return v;
}

// K1: per (b,n) wave: scores[b,r,n] (beta folded in), a[b,r,n]=(1-ww)*prw,
//     Ldiag[b,n] = L[b,n,n]
__global__ __launch_bounds__(256) void k1_prep(
    const float* __restrict__ mem, const float* __restrict__ ctr,
    const float* __restrict__ ww, const float* __restrict__ prw,
    const float* __restrict__ L,
    float* __restrict__ scores, float* __restrict__ a_arr,
    float* __restrict__ Ldiag){
  int wid = threadIdx.x >> 6, lane = threadIdx.x & 63;
  int g = blockIdx.x * 4 + wid;        // wave id == (b,n)
  int b = g >> 11, n = g & (NN-1);
  float m = mem[((size_t)(b*NN + n))*WWID + lane];
  const float* cb = ctr + b*CTRL;
  float k0 = cb[0*WWID+lane], k1 = cb[1*WWID+lane];
  float k2 = cb[2*WWID+lane], k3 = cb[3*WWID+lane];
  float s0 = m*m;
  float d0 = m*k0, d1 = m*k1, d2 = m*k2, d3 = m*k3;
  float q0 = k0*k0, q1 = k1*k1, q2 = k2*k2, q3 = k3*k3;
#pragma unroll
  for (int t=1;t<64;t<<=1){
    s0 += __shfl_xor(s0,t);
    d0 += __shfl_xor(d0,t); d1 += __shfl_xor(d1,t);
    d2 += __shfl_xor(d2,t); d3 += __shfl_xor(d3,t);
    q0 += __shfl_xor(q0,t); q1 += __shfl_xor(q1,t);
    q2 += __shfl_xor(q2,t); q3 += __shfl_xor(q3,t);
  }
  if (lane==0){
    float mn = sqrtf(s0);
    float be[4];
#pragma unroll
    for (int r=0;r<4;r++){
      float x = cb[RNUM*WWID + r];
      be[r] = 1.f + (x > 20.f ? x : log1pf(expf(x)));
    }
    scores[(b*RNUM+0)*NN+n] = d0*be[0]/(sqrtf(q0)*mn + EPSF);
    scores[(b*RNUM+1)*NN+n] = d1*be[1]/(sqrtf(q1)*mn + EPSF);
    scores[(b*RNUM+2)*NN+n] = d2*be[2]/(sqrtf(q2)*mn + EPSF);
    scores[(b*RNUM+3)*NN+n] = d3*be[3]/(sqrtf(q3)*mn + EPSF);
    Ldiag[b*NN+n] = L[((size_t)(b*NN+n))*NN + n];
  }
  if (lane < RNUM){
    int r = lane;
    a_arr[(b*RNUM+r)*NN+n] = (1.f - ww[b*NN+n]) * prw[(b*RNUM+r)*NN+n];
  }
}

// K2: per (b,r): scalars {g0,g1,g2,S,T,mx,inv_sum}.  1024 threads, 2 elems each.
__global__ __launch_bounds__(1024) void k2_head(
    const float* __restrict__ ctr, const float* __restrict__ scores,
    const float* __restrict__ ww, const float* __restrict__ prec,
    const float* __restrict__ prw, float* __restrict__ scal){
  __shared__ float redm[16], redS[16], redT[16], reds[16];
  int tid = threadIdx.x, wid = tid>>6, lane = tid&63;
  int b = blockIdx.x >> 2, r = blockIdx.x & 3;
  const float* sc = scores + (size_t)(b*RNUM+r)*NN;
  const float* pr = prw    + (size_t)(b*RNUM+r)*NN;
  float s0 = sc[tid], s1 = sc[tid+1024];
  float p0 = pr[tid], p1 = pr[tid+1024];
  float lmax = fmaxf(s0, s1);
  float lS = prec[b*NN+tid]*p0 + prec[b*NN+tid+1024]*p1;
  float lT = ww[b*NN+tid]*p0   + ww[b*NN+tid+1024]*p1;
  lmax = wred_max(lmax); lS = wred_sum(lS); lT = wred_sum(lT);
  if (lane==0){ redm[wid]=lmax; redS[wid]=lS; redT[wid]=lT; }
  __syncthreads();
  float mx=-1e30f, S=0.f, T=0.f;
#pragma unroll
  for (int i=0;i<16;i++){ mx=fmaxf(mx,redm[i]); S+=redS[i]; T+=redT[i]; }
  float ls = expf(s0-mx) + expf(s1-mx);
  ls = wred_sum(ls);
  if (lane==0) reds[wid]=ls;
  __syncthreads();
  float sum=0.f;
#pragma unroll
  for (int i=0;i<16;i++) sum += reds[i];
  if (tid==0){
    const float* cb = ctr + b*CTRL;
    float c0 = cb[RNUM*WWID + RNUM + r*3 + 0];
    float c1 = cb[RNUM*WWID + RNUM + r*3 + 1];
    float c2 = cb[RNUM*WWID + RNUM + r*3 + 2];
    float mg = fmaxf(c0, fmaxf(c1, c2));
    float e0 = expf(c0-mg), e1 = expf(c1-mg), e2 = expf(c2-mg);
    float inv3 = 1.f/(e0+e1+e2);
    float* s = &scal[(b*RNUM+r)*8];
    s[0]=e0*inv3; s[1]=e1*inv3; s[2]=e2*inv3;
    s[3]=S; s[4]=T; s[5]=mx; s[6]=1.f/sum;
  }
}

// K3: single streaming pass over prev_links, 32 rows x 512 cols per block.
// fwd_part[b,cq,r,i] = sum_{j in cq} L[i,j]*(a_r[j] - ww_i*prw_r[j])
// part[b,tile,r,j]   = sum_{i in tile} L[i,j]*(a_r[i] - ww_j*prw_r[i])
__global__ __launch_bounds__(256) void k3_links(
    const float* __restrict__ L, const float* __restrict__ ww,
    const float* __restrict__ prw, const float* __restrict__ a_arr,
    float* __restrict__ fwd_part, float* __restrict__ part){
  __shared__ float lrow[TI][16];       // {ww, pad x3, a0..a3, p0..p3}
  __shared__ float lcol[4096];         // [wave][r][256 cols] conflict-free
  int tid = threadIdx.x, wid = tid>>6, lane = tid&63;
  int bid = blockIdx.x;
  int b   = bid >> 8;                  // / (TILES*CQ)
  int rem = bid & 255;
  int tile = rem >> 2, cq = rem & 3;
  int i0 = tile*TI, jbase = cq*512;
  if (tid < TI){
    int i = i0 + tid;
    lrow[tid][0] = ww[b*NN + i];
#pragma unroll
    for (int r=0;r<RNUM;r++){
      lrow[tid][4+r] = a_arr[(b*RNUM+r)*NN + i];
      lrow[tid][8+r] = prw[(b*RNUM+r)*NN + i];
    }
  }
  __syncthreads();
  float accf[32];                      // index rr*4 + r
#pragma unroll
  for (int k=0;k<32;k++) accf[k]=0.f;

  for (int c=0;c<2;c++){
    int j0 = jbase + c*256 + lane*4;
    float4 a4[4], p4[4];
#pragma unroll
    for (int r=0;r<4;r++){
      a4[r] = *reinterpret_cast<const float4*>(&a_arr[(b*RNUM+r)*NN + j0]);
      p4[r] = *reinterpret_cast<const float4*>(&prw[(b*RNUM+r)*NN + j0]);
    }
    float4 wwj = *reinterpret_cast<const float4*>(&ww[b*NN + j0]);
    float4 cacc[4];
#pragma unroll
    for (int r=0;r<4;r++){ cacc[r].x=0.f; cacc[r].y=0.f; cacc[r].z=0.f; cacc[r].w=0.f; }

#pragma unroll
    for (int rr=0; rr<8; rr++){
      int lr = wid*8 + rr;
      int i  = i0 + lr;
      float wwi = lrow[lr][0];
      float4 ai4 = *reinterpret_cast<const float4*>(&lrow[lr][4]);
      float4 pi4 = *reinterpret_cast<const float4*>(&lrow[lr][8]);
      float4 L4 = *reinterpret_cast<const float4*>(&L[((size_t)(b*NN + i))*NN + j0]);
#pragma unroll
      for (int r=0;r<4;r++){
        float4 ar = a4[r], pr = p4[r];
        float mx_ = fmaf(-wwi, pr.x, ar.x);
        float my_ = fmaf(-wwi, pr.y, ar.y);
        float mz_ = fmaf(-wwi, pr.z, ar.z);
        float mw_ = fmaf(-wwi, pr.w, ar.w);
        float s = accf[rr*4+r];
        s = fmaf(L4.x, mx_, s); s = fmaf(L4.y, my_, s);
        s = fmaf(L4.z, mz_, s); s = fmaf(L4.w, mw_, s);
        accf[rr*4+r] = s;
        float ai = (r==0)?ai4.x:((r==1)?ai4.y:((r==2)?ai4.z:ai4.w));
        float pi = (r==0)?pi4.x:((r==1)?pi4.y:((r==2)?pi4.z:pi4.w));
        float nx_ = fmaf(-wwj.x, pi, ai);
        float ny_ = fmaf(-wwj.y, pi, ai);
        float nz_ = fmaf(-wwj.z, pi, ai);
        float nw_ = fmaf(-wwj.w, pi, ai);
        cacc[r].x = fmaf(L4.x, nx_, cacc[r].x);
        cacc[r].y = fmaf(L4.y, ny_, cacc[r].y);
        cacc[r].z = fmaf(L4.z, nz_, cacc[r].z);
        cacc[r].w = fmaf(L4.w, nw_, cacc[r].w);
      }
    }
    __syncthreads();   // prior combine-reads done before overwrite
#pragma unroll
    for (int r=0;r<4;r++)
      *reinterpret_cast<float4*>(&lcol[wid*1024 + r*256 + lane*4]) = cacc[r];
    __syncthreads();
    // combine 4 waves; thread (wid,lane) owns (r=wid, cols lane*4..+3)
    float4 v; v.x=0.f; v.y=0.f; v.z=0.f; v.w=0.f;
#pragma unroll
    for (int w=0;w<4;w++){
      float4 t = *reinterpret_cast<const float4*>(&lcol[w*1024 + wid*256 + lane*4]);
      v.x+=t.x; v.y+=t.y; v.z+=t.z; v.w+=t.w;
    }
    *reinterpret_cast<float4*>(
      &part[((size_t)((b*TILES+tile)*RNUM + wid))*NN + jbase + c*256 + lane*4]) = v;
  }

  // packed butterfly: 32 per-lane values -> lane k holds total for value k
#pragma unroll
  for (int k=0;k<32;k++) accf[k] += __shfl_xor(accf[k], 32);
#pragma unroll
  for (int h=16; h>=1; h>>=1){
#pragma unroll
    for (int i=0;i<h;i++){
      float a = accf[i], bb = accf[i+h];
      bool up = (lane & h) != 0;
      float lo = up ? bb : a;
      float hi = up ? a : bb;
      accf[i] = lo + __shfl_xor(hi, h);
    }
  }
  if (lane < 32){
    int k = lane;                       // value index: rr = k>>2, r = k&3
    fwd_part[((size_t)(b*CQ + cq)*RNUM + (k&3))*NN + i0 + wid*8 + (k>>2)] = accf[0];
  }
}

// K4: reduce partials + epilogue -> read_weights
__global__ __launch_bounds__(256) void k4_combine(
    const float* __restrict__ part, const float* __restrict__ fwd_part,
    const float* __restrict__ scores, const float* __restrict__ scal,
    const float* __restrict__ ww, const float* __restrict__ prec,
    const float* __restrict__ prw, const float* __restrict__ Ldiag,
    float* __restrict__ rw){
  int b = blockIdx.x >> 5, rem = blockIdx.x & 31;
  int r = rem >> 3, nb = rem & 7;
  int n = nb*256 + threadIdx.x;
  const float* s = &scal[(b*RNUM+r)*8];
  float g0=s[0], g1=s[1], g2=s[2], S=s[3], T=s[4], mx=s[5], inv=s[6];
  const float* pp = part + ((size_t)(b*TILES)*RNUM + r)*NN + n;
  float b0=0.f,b1=0.f,b2=0.f,b3=0.f;
  for (int t=0;t<TILES;t+=4){
    b0 += pp[(size_t)(t+0)*RNUM*NN];
    b1 += pp[(size_t)(t+1)*RNUM*NN];
    b2 += pp[(size_t)(t+2)*RNUM*NN];
    b3 += pp[(size_t)(t+3)*RNUM*NN];
  }
  float bsum = (b0+b1)+(b2+b3);
  float fsum = 0.f;
#pragma unroll
  for (int cq=0;cq<CQ;cq++)
    fsum += fwd_part[((size_t)(b*CQ + cq)*RNUM + r)*NN + n];
  float wwn = ww[b*NN+n], pn = prec[b*NN+n], prn = prw[(b*RNUM+r)*NN+n];
  float Lnn = Ldiag[b*NN+n];
  float diag = (fmaf(-2.f*wwn, Lnn, Lnn) + wwn*pn) * prn;
  float fwd = fsum + wwn*S - diag;
  float bwd = bsum + pn*T - diag;
  float content = expf(scores[(b*RNUM+r)*NN+n] - mx) * inv;
  rw[(b*RNUM+r)*NN+n] = g0*fwd + g1*bwd + g2*content;
}

// K5: read_vector[b,r,w] = sum_n memory[b,n,w]*rw[b,r,n]
__global__ __launch_bounds__(256) void k5_read(
    const float* __restrict__ mem, const float* __restrict__ rw,
    float* __restrict__ out){
  __shared__ float rwl[256];
  int tid = threadIdx.x;
  int b = blockIdx.x >> 5, ch = blockIdx.x & 31;
  int n0 = ch*64;
  int r = tid >> 6, nn = tid & 63;
  rwl[tid] = rw[(b*RNUM+r)*NN + n0 + nn];
  __syncthreads();
  int wid = tid>>6, lane = tid&63;     // wave == r
  float acc = 0.f;
#pragma unroll 4
  for (int q=0; q<64; q++)
    acc = fmaf(mem[((size_t)(b*NN + n0 + q))*WWID + lane], rwl[wid*64+q], acc);
  atomicAdd(&out[(b*RNUM+wid)*WWID + lane], acc);
}

extern "C" void kernel_launch(void* const* d_in, const int* in_sizes, int n_in,
                              void* d_out, int out_size, void* d_ws, size_t ws_size,
                              hipStream_t stream){
  const float* mem  = (const float*)d_in[0];
  const float* ctr  = (const float*)d_in[1];
  const float* ww   = (const float*)d_in[2];
  const float* L    = (const float*)d_in[3];
  const float* prec = (const float*)d_in[4];
  const float* prw  = (const float*)d_in[5];
  float* out = (float*)d_out;
  float* w = (float*)d_ws;

  float* scores   = w;                        // B*R*N
  float* a_arr    = scores + BB*RNUM*NN;      // B*R*N
  float* Ldiag    = a_arr + BB*RNUM*NN;       // B*N
  float* scal     = Ldiag + BB*NN;            // 256
  float* fwd_part = scal + 256;               // B*CQ*R*N
  float* rw       = fwd_part + BB*CQ*RNUM*NN; // B*R*N
  float* part     = rw + BB*RNUM*NN;          // B*TILES*R*N

  hipMemsetAsync(out, 0, (size_t)BB*RNUM*WWID*sizeof(float), stream);
  k1_prep<<<BB*NN/4, 256, 0, stream>>>(mem, ctr, ww, prw, L, scores, a_arr, Ldiag);
  k2_head<<<BB*RNUM, 1024, 0, stream>>>(ctr, scores, ww, prec, prw, scal);
  k3_links<<<BB*TILES*CQ, 256, 0, stream>>>(L, ww, prw, a_arr, fwd_part, part);
  k4_combine<<<BB*RNUM*8, 256, 0, stream>>>(part, fwd_part, scores, scal, ww, prec, prw, Ldiag, rw);
  k5_read<<<BB*32, 256, 0, stream>>>(mem, rw, out);
}